// Round 12
// baseline (247.683 us; speedup 1.0000x reference)
//
#include <hip/hip_runtime.h>

typedef __bf16 bf16x8 __attribute__((ext_vector_type(8)));
typedef __bf16 bf16x4 __attribute__((ext_vector_type(4)));
typedef float  floatx4 __attribute__((ext_vector_type(4)));

#define GLOBAL_AS __attribute__((address_space(1)))
#define LOCAL_AS  __attribute__((address_space(3)))

static constexpr int HID = 1024;
static constexpr int MT  = 128;  // samples per block
static constexpr int BK  = 64;   // K per staging iter
static constexpr int KIT = HID / BK;  // 16

__device__ __forceinline__ void h8(bf16x8& d, float s0, float s1,
                                   const float4& w0a, const float4& w0b,
                                   const float4& w1a, const float4& w1b,
                                   const float4& ba,  const float4& bb) {
    d[0] = (__bf16)fmaxf(fmaf(s1, w1a.x, fmaf(s0, w0a.x, ba.x)), 0.f);
    d[1] = (__bf16)fmaxf(fmaf(s1, w1a.y, fmaf(s0, w0a.y, ba.y)), 0.f);
    d[2] = (__bf16)fmaxf(fmaf(s1, w1a.z, fmaf(s0, w0a.z, ba.z)), 0.f);
    d[3] = (__bf16)fmaxf(fmaf(s1, w1a.w, fmaf(s0, w0a.w, ba.w)), 0.f);
    d[4] = (__bf16)fmaxf(fmaf(s1, w1b.x, fmaf(s0, w0b.x, bb.x)), 0.f);
    d[5] = (__bf16)fmaxf(fmaf(s1, w1b.y, fmaf(s0, w0b.y, bb.y)), 0.f);
    d[6] = (__bf16)fmaxf(fmaf(s1, w1b.z, fmaf(s0, w0b.z, bb.z)), 0.f);
    d[7] = (__bf16)fmaxf(fmaf(s1, w1b.w, fmaf(s0, w0b.w, bb.w)), 0.f);
}

// ---------------------------------------------------------------------------
// Fused prep, one dispatch. Block ranges (weight preps FIRST):
//   [0, ex)        : chunk 0 only — ex=288: W2->W2T (256 blks, r1-verified)
//                    + W_heads->WHT (32 blks, r2-verified)
//   [ex, ex+nz)    : zero OUT rows [row0, row0+Mc)
//   [ex+nz, +nh)   : H = relu(s@W1+b1), 16 rows/wave, weights hoisted once.
//                    PLAIN stores (r11's NT stores evicted H from L2/LLC and
//                    cost policy_main ~11 us of HBM re-reads — reverted).
// Swizzle relations identical to r6-r9 -> policy_main reads unchanged.
// ---------------------------------------------------------------------------
__global__ __launch_bounds__(256)
void prep_all(const float* __restrict__ S,  const float* __restrict__ W1,
              const float* __restrict__ B1, const float* __restrict__ W2,
              const float* __restrict__ WH,
              __bf16* __restrict__ H, __bf16* __restrict__ W2T,
              __bf16* __restrict__ WHT, float* __restrict__ OUT,
              int row0, int ex, int nz) {
    const int tid = threadIdx.x;
    if (blockIdx.x < (unsigned)ex) {
        const int b = blockIdx.x;
        if (b < 256) {
            // ---- W2 [K][N] fp32 -> W2T [N][K] bf16, octet g stored at g^(n&7)
            __shared__ __bf16 tile[64][65];
            const int bx = b & 15;   // n-tile
            const int by = b >> 4;   // k-tile
            const int a  = tid & 63;
            const int b4 = tid >> 6;  // 0..3
#pragma unroll
            for (int r = 0; r < 16; ++r) {
                const int k = r * 4 + b4;
                tile[a][k] = (__bf16)W2[(size_t)(by * 64 + k) * HID + bx * 64 + a];
            }
            __syncthreads();
#pragma unroll
            for (int r = 0; r < 16; ++r) {
                const int n = r * 4 + b4;
                const int g = a >> 3, j = a & 7;
                W2T[(size_t)(bx * 64 + n) * HID + by * 64
                    + (((g ^ (n & 7)) << 3) | j)] = tile[n][a];
            }
        } else {
            // ---- W_heads [5][H][4] -> WHT [32][H] bf16 (rows 20..31 zero)
            const int r = b - 256;             // 0..31
            const int s = r >> 2, a = r & 3;
            for (int k = tid; k < HID; k += 256) {
                const float v = (r < 20) ? WH[((size_t)s * HID + k) * 4 + a] : 0.f;
                const int c = k >> 7, o = (k >> 3) & 15, j = k & 7;
                WHT[(size_t)r * HID + c * 128
                    + ((o & 8) | ((o & 7) ^ (r & 7))) * 8 + j] = (__bf16)v;
            }
        }
        return;
    }
    int b = blockIdx.x - ex;
    if (b < nz) {
        // ---- zero OUT for this chunk's rows (one float4 = one sample)
        ((float4*)OUT)[(size_t)row0 + (size_t)b * 256 + tid]
            = make_float4(0.f, 0.f, 0.f, 0.f);
        return;
    }
    b -= nz;
    // ---- H: wave -> 16 rows, lane -> cols c0..c0+7 (sections 0 and 512)
    const int wid  = b * 4 + (tid >> 6);
    const int lane = tid & 63;
    const int rb   = wid * 16;              // chunk-local row base
    const int c0   = lane * 8;
    // hoist every weight/bias load: one latency window, then store stream
    const float4 w0a0 = *(const float4*)(W1 + c0);
    const float4 w0b0 = *(const float4*)(W1 + c0 + 4);
    const float4 w1a0 = *(const float4*)(W1 + HID + c0);
    const float4 w1b0 = *(const float4*)(W1 + HID + c0 + 4);
    const float4 ba0  = *(const float4*)(B1 + c0);
    const float4 bb0  = *(const float4*)(B1 + c0 + 4);
    const float4 w0a1 = *(const float4*)(W1 + 512 + c0);
    const float4 w0b1 = *(const float4*)(W1 + 512 + c0 + 4);
    const float4 w1a1 = *(const float4*)(W1 + HID + 512 + c0);
    const float4 w1b1 = *(const float4*)(W1 + HID + 512 + c0 + 4);
    const float4 ba1  = *(const float4*)(B1 + 512 + c0);
    const float4 bb1  = *(const float4*)(B1 + 512 + c0 + 4);
    float2 sv[16];
#pragma unroll
    for (int r = 0; r < 16; ++r)
        sv[r] = *(const float2*)(S + (size_t)(row0 + rb + r) * 2);
#pragma unroll
    for (int r = 0; r < 16; ++r) {
        const int rl = rb + r;
        const int xo = ((((c0 >> 3) & 7) ^ (rl & 7)) << 3);
        bf16x8 hv0, hv1;
        h8(hv0, sv[r].x, sv[r].y, w0a0, w0b0, w1a0, w1b0, ba0, bb0);
        h8(hv1, sv[r].x, sv[r].y, w0a1, w0b1, w1a1, w1b1, ba1, bb1);
        *(bf16x8*)(H + (size_t)rl * HID + ((c0 & ~63) | xo))       = hv0;
        *(bf16x8*)(H + (size_t)rl * HID + ((c0 & ~63) | xo) + 512) = hv1;
    }
}

// ---------------------------------------------------------------------------
// Pure m97-form GEMM + fused head (r6-r9 verified: 153 us, ~900 TF eff).
// BYTE-IDENTICAL to round 9's policy_main. 256 threads / 4 waves, 128x128
// tile, BK=64, A (=H) and B (=W2T) via global_load_lds width-16, 2 barriers
// per iter, LDS 40960 B -> 4 blocks/CU. XCD grouping: n8 = blockIdx>>mg_bits.
// ---------------------------------------------------------------------------
__global__ __launch_bounds__(256, 4)
void policy_main(const __bf16* __restrict__ H, const int* __restrict__ SK,
                 const __bf16* __restrict__ W2T, const float* __restrict__ B2,
                 const __bf16* __restrict__ WHT, const float* __restrict__ BH,
                 float* __restrict__ OUT, int row0, int mg_bits) {
    __shared__ __align__(16) char smem[40960];
    __bf16* hA    = (__bf16*)smem;            // [128][64]
    __bf16* Bt    = (__bf16*)(smem + 16384);  // [128][64]
    __bf16* featL = (__bf16*)smem;            // overlay [128][128] swizzled
    __bf16* WHTL  = (__bf16*)(smem + 32768);  // [32][128]

    const int tid  = threadIdx.x;
    const int lane = tid & 63;
    const int wv   = tid >> 6;   // 0..3
    const int wm   = wv & 1;     // sample strip of 64
    const int wn   = wv >> 1;    // featcol strip of 64
    const int l15  = lane & 15;
    const int quad = lane >> 4;
    const int n8   = blockIdx.x >> mg_bits;
    const int i0l  = (blockIdx.x & ((1 << mg_bits) - 1)) * MT;  // chunk-local

    floatx4 acc[4][4] = {};    // [fn featcol-frag][fm sample-frag]
    floatx4 hacc[2][2] = {};   // head acc [sample-frag][headcol-tile]

    // ---- prologue: stage WHTL [32][128] once (kt-invariant)
#pragma unroll
    for (int c = 0; c < 2; ++c) {
        const int rb = c * 16 + wv * 4;
        const __bf16* gp = WHT + (size_t)(rb + (lane >> 4)) * HID
                         + n8 * 128 + (lane & 15) * 8;
        __builtin_amdgcn_global_load_lds((GLOBAL_AS void*)gp,
                                         (LOCAL_AS void*)(WHTL + rb * 128), 16, 0, 0);
    }

#pragma unroll 1
    for (int kt = 0; kt < KIT; ++kt) {
        __syncthreads();  // previous iter's frag readers done
        // ---- stage A from H: 4 global_load_lds per thread
#pragma unroll
        for (int c = 0; c < 4; ++c) {
            const int rb = c * 32 + wv * 8;
            const __bf16* gp = H + (size_t)(i0l + rb + (lane >> 3)) * HID
                             + kt * BK + (lane & 7) * 8;
            __builtin_amdgcn_global_load_lds((GLOBAL_AS void*)gp,
                                             (LOCAL_AS void*)(hA + rb * 64), 16, 0, 0);
        }
        // ---- stage B from W2T slab n8
#pragma unroll
        for (int c = 0; c < 4; ++c) {
            const int rb = c * 32 + wv * 8;
            const __bf16* gp = W2T + (size_t)(n8 * 128 + rb + (lane >> 3)) * HID
                             + kt * BK + (lane & 7) * 8;
            __builtin_amdgcn_global_load_lds((GLOBAL_AS void*)gp,
                                             (LOCAL_AS void*)(Bt + rb * 64), 16, 0, 0);
        }
        __syncthreads();  // drain staging
        // ---- 2 k-steps of 32: 8 frag reads + 16 MFMA each
#pragma unroll
        for (int ks = 0; ks < 2; ++ks) {
            bf16x8 wf[4], hf[4];
#pragma unroll
            for (int f = 0; f < 4; ++f) {
                const int row = wn * 64 + f * 16 + l15;   // featcol (local)
                wf[f] = *(const bf16x8*)(Bt + row * 64 + (((ks * 4 + quad) ^ (row & 7)) * 8));
            }
#pragma unroll
            for (int f = 0; f < 4; ++f) {
                const int smp = wm * 64 + f * 16 + l15;
                hf[f] = *(const bf16x8*)(hA + smp * 64 + (((ks * 4 + quad) ^ (smp & 7)) * 8));
            }
#pragma unroll
            for (int fn = 0; fn < 4; ++fn)
#pragma unroll
                for (int fm = 0; fm < 4; ++fm)
                    acc[fn][fm] = __builtin_amdgcn_mfma_f32_16x16x32_bf16(
                        wf[fn], hf[fm], acc[fn][fm], 0, 0, 0);
        }
    }

    // ---- epilogue: relu(acc+b2) -> featL (swizzled, overlays hA+Bt)
    __syncthreads();  // K-loop frag readers done before overlay
#pragma unroll
    for (int fn = 0; fn < 4; ++fn) {
        const int fcb = wn * 64 + fn * 16 + quad * 4;   // featcol base 0..124
        const float4 b2v = *(const float4*)(B2 + n8 * 128 + fcb);
#pragma unroll
        for (int fm = 0; fm < 4; ++fm) {
            const int smp = wm * 64 + fm * 16 + l15;
            const floatx4 v = acc[fn][fm];
            bf16x4 p;
            p[0] = (__bf16)fmaxf(v[0] + b2v.x, 0.f);
            p[1] = (__bf16)fmaxf(v[1] + b2v.y, 0.f);
            p[2] = (__bf16)fmaxf(v[2] + b2v.z, 0.f);
            p[3] = (__bf16)fmaxf(v[3] + b2v.w, 0.f);
            *(bf16x4*)(featL + smp * 128 + (((fcb >> 3) ^ (smp & 15)) << 3) + (fcb & 7)) = p;
        }
    }
    __syncthreads();

    // ---- head MFMA: wave w -> samples w*32..+31, K = this block's 128 cols
#pragma unroll
    for (int f2 = 0; f2 < 2; ++f2) {
#pragma unroll
        for (int ks2 = 0; ks2 < 4; ++ks2) {
            const int row = wv * 32 + f2 * 16 + l15;
            const bf16x8 fa = *(const bf16x8*)(featL + row * 128
                                 + (((ks2 * 4 + quad) ^ (row & 15)) << 3));
#pragma unroll
            for (int t2 = 0; t2 < 2; ++t2) {
                const int r = t2 * 16 + l15;
                const int o = ks2 * 4 + quad;
                const int sw = (o & 8) | ((o & 7) ^ (r & 7));
                const bf16x8 wb = *(const bf16x8*)(WHTL + r * 128 + sw * 8);
                hacc[f2][t2] = __builtin_amdgcn_mfma_f32_16x16x32_bf16(
                    fa, wb, hacc[f2][t2], 0, 0, 0);
            }
        }
    }

    // ---- atomic scatter from registers: C-layout sample = quad*4+reg,
    //      headcol = t2*16 + l15; emit only the selected skill's 4 actions
#pragma unroll
    for (int f2 = 0; f2 < 2; ++f2)
#pragma unroll
        for (int j = 0; j < 4; ++j) {
            const int smp = wv * 32 + f2 * 16 + quad * 4 + j;
            const int sk  = SK[(size_t)row0 + i0l + smp];
#pragma unroll
            for (int t2 = 0; t2 < 2; ++t2) {
                const int hc = t2 * 16 + l15;
                const int d  = hc - sk * 4;
                if (d >= 0 && d < 4) {
                    float v = hacc[f2][t2][j];
                    if (n8 == 0) v += BH[hc];
                    atomicAdd(&OUT[(size_t)(row0 + i0l + smp) * 4 + d], v);
                }
            }
        }
}

extern "C" void kernel_launch(void* const* d_in, const int* in_sizes, int n_in,
                              void* d_out, int out_size, void* d_ws, size_t ws_size,
                              hipStream_t stream) {
    const float* S  = (const float*)d_in[0];
    const int*   SK = (const int*)d_in[1];
    const float* W1 = (const float*)d_in[2];
    const float* B1 = (const float*)d_in[3];
    const float* W2 = (const float*)d_in[4];
    const float* B2 = (const float*)d_in[5];
    const float* WH = (const float*)d_in[6];
    const float* BH = (const float*)d_in[7];

    char* ws = (char*)d_ws;
    __bf16* W2T = (__bf16*)ws;                          // 2 MiB
    __bf16* WHT = (__bf16*)(ws + 2 * 1024 * 1024);      // 64 KiB
    __bf16* H   = (__bf16*)(ws + 2 * 1024 * 1024 + 65536);

    // chunk the batch so H fits in the workspace (deterministic per call)
    const size_t fixed = 2 * 1024 * 1024 + 65536;
    const size_t avail = ws_size > fixed ? ws_size - fixed : 0;
    int nc = 1;
    while (nc < 64 && (size_t)(65536 / nc) * HID * sizeof(__bf16) > avail) nc <<= 1;
    const int Mc = 65536 / nc;
    int mg_bits = 0;
    while ((1 << mg_bits) < Mc / MT) ++mg_bits;   // Mc/MT is a power of two

    for (int c = 0; c < nc; ++c) {
        const int nh = Mc / 64;                   // H blocks (16 rows/wave)
        const int nz = Mc / 256;                  // OUT-zero blocks
        const int ex = (c == 0) ? 288 : 0;        // weight preps once, first
        hipLaunchKernelGGL(prep_all, dim3(ex + nz + nh), dim3(256), 0, stream,
                           S, W1, B1, W2, WH, H, W2T, WHT, (float*)d_out,
                           c * Mc, ex, nz);
        hipLaunchKernelGGL(policy_main, dim3((Mc / MT) * 8), dim3(256), 0, stream,
                           H, SK, W2T, B2, WHT, BH, (float*)d_out, c * Mc, mg_bits);
    }
}

// Round 13
// 239.269 us; speedup vs baseline: 1.0352x; 1.0352x over previous
//
#include <hip/hip_runtime.h>

typedef __bf16 bf16x8 __attribute__((ext_vector_type(8)));
typedef __bf16 bf16x4 __attribute__((ext_vector_type(4)));
typedef float  floatx4 __attribute__((ext_vector_type(4)));

#define GLOBAL_AS __attribute__((address_space(1)))
#define LOCAL_AS  __attribute__((address_space(3)))

static constexpr int HID = 1024;
static constexpr int MT  = 128;  // samples per block
static constexpr int BK  = 64;   // K per staging iter
static constexpr int KIT = HID / BK;  // 16

__device__ __forceinline__ void h8(bf16x8& d, float s0, float s1,
                                   const float4& w0a, const float4& w0b,
                                   const float4& w1a, const float4& w1b,
                                   const float4& ba,  const float4& bb) {
    d[0] = (__bf16)fmaxf(fmaf(s1, w1a.x, fmaf(s0, w0a.x, ba.x)), 0.f);
    d[1] = (__bf16)fmaxf(fmaf(s1, w1a.y, fmaf(s0, w0a.y, ba.y)), 0.f);
    d[2] = (__bf16)fmaxf(fmaf(s1, w1a.z, fmaf(s0, w0a.z, ba.z)), 0.f);
    d[3] = (__bf16)fmaxf(fmaf(s1, w1a.w, fmaf(s0, w0a.w, ba.w)), 0.f);
    d[4] = (__bf16)fmaxf(fmaf(s1, w1b.x, fmaf(s0, w0b.x, bb.x)), 0.f);
    d[5] = (__bf16)fmaxf(fmaf(s1, w1b.y, fmaf(s0, w0b.y, bb.y)), 0.f);
    d[6] = (__bf16)fmaxf(fmaf(s1, w1b.z, fmaf(s0, w0b.z, bb.z)), 0.f);
    d[7] = (__bf16)fmaxf(fmaf(s1, w1b.w, fmaf(s0, w0b.w, bb.w)), 0.f);
}

// ---------------------------------------------------------------------------
// Fused prep, one dispatch — EXACT round-9 form (best measured: 239.8 us
// total, main 153 us). Block ranges:
//   [0, nh)           : H = relu(s@W1+b1), 8 rows/wave, weights hoisted
//   [nh, nh+nz)       : zero OUT rows [row0, row0+Mc)
//   [nh+nz, +256)     : W2 -> W2T (r1-verified)        [chunk 0 only]
//   [nh+nz+256, +288) : W_heads -> WHT (r2-verified)   [chunk 0 only]
// Weight preps LAST: W2T/WHT land freshly in L2 right before policy_main.
// (r11/r12's weights-first + 16-rows variants measured neutral-to-worse.)
// ---------------------------------------------------------------------------
__global__ __launch_bounds__(256)
void prep_all(const float* __restrict__ S,  const float* __restrict__ W1,
              const float* __restrict__ B1, const float* __restrict__ W2,
              const float* __restrict__ WH,
              __bf16* __restrict__ H, __bf16* __restrict__ W2T,
              __bf16* __restrict__ WHT, float* __restrict__ OUT,
              int row0, int nh, int nz) {
    if (blockIdx.x < (unsigned)nh) {
        // ---- H: wave -> 8 rows, lane -> cols c..c+7 (sections 0 and 512)
        const int wid  = blockIdx.x * 4 + (threadIdx.x >> 6);
        const int lane = threadIdx.x & 63;
        const int rb   = wid * 8;               // chunk-local row base
        const int c0   = lane * 8;
        // hoist every weight/bias load: one latency window, then pure stores
        const float4 w0a0 = *(const float4*)(W1 + c0);
        const float4 w0b0 = *(const float4*)(W1 + c0 + 4);
        const float4 w1a0 = *(const float4*)(W1 + HID + c0);
        const float4 w1b0 = *(const float4*)(W1 + HID + c0 + 4);
        const float4 ba0  = *(const float4*)(B1 + c0);
        const float4 bb0  = *(const float4*)(B1 + c0 + 4);
        const float4 w0a1 = *(const float4*)(W1 + 512 + c0);
        const float4 w0b1 = *(const float4*)(W1 + 512 + c0 + 4);
        const float4 w1a1 = *(const float4*)(W1 + HID + 512 + c0);
        const float4 w1b1 = *(const float4*)(W1 + HID + 512 + c0 + 4);
        const float4 ba1  = *(const float4*)(B1 + 512 + c0);
        const float4 bb1  = *(const float4*)(B1 + 512 + c0 + 4);
        float2 sv[8];
#pragma unroll
        for (int r = 0; r < 8; ++r)
            sv[r] = *(const float2*)(S + (size_t)(row0 + rb + r) * 2);
#pragma unroll
        for (int r = 0; r < 8; ++r) {
            const int rl = rb + r;
            const int xo = ((((c0 >> 3) & 7) ^ (rl & 7)) << 3);
            bf16x8 hv0, hv1;
            h8(hv0, sv[r].x, sv[r].y, w0a0, w0b0, w1a0, w1b0, ba0, bb0);
            h8(hv1, sv[r].x, sv[r].y, w0a1, w0b1, w1a1, w1b1, ba1, bb1);
            *(bf16x8*)(H + (size_t)rl * HID + ((c0 & ~63) | xo))       = hv0;
            *(bf16x8*)(H + (size_t)rl * HID + ((c0 & ~63) | xo) + 512) = hv1;
        }
        return;
    }
    int b = blockIdx.x - nh;
    if (b < nz) {
        // ---- zero OUT for this chunk's rows (one float4 = one sample)
        ((float4*)OUT)[(size_t)row0 + (size_t)b * 256 + threadIdx.x]
            = make_float4(0.f, 0.f, 0.f, 0.f);
        return;
    }
    b -= nz;
    if (b < 256) {
        // ---- W2 [K][N] fp32 -> W2T [N][K] bf16, octet g stored at g^(n&7)
        __shared__ __bf16 tile[64][65];
        const int bx = b & 15;   // n-tile
        const int by = b >> 4;   // k-tile
        const int a  = threadIdx.x & 63;
        const int bb = threadIdx.x >> 6;  // 0..3
#pragma unroll
        for (int r = 0; r < 16; ++r) {
            const int k = r * 4 + bb;
            tile[a][k] = (__bf16)W2[(size_t)(by * 64 + k) * HID + bx * 64 + a];
        }
        __syncthreads();
#pragma unroll
        for (int r = 0; r < 16; ++r) {
            const int n = r * 4 + bb;
            const int g = a >> 3, j = a & 7;
            const int ksw = ((g ^ (n & 7)) << 3) | j;
            W2T[(size_t)(bx * 64 + n) * HID + by * 64 + ksw] = tile[n][a];
        }
    } else {
        // ---- W_heads [5][H][4] -> WHT [32][H] bf16 (rows 20..31 zero)
        const int r = b - 256;             // 0..31
        const int s = r >> 2, a = r & 3;
        for (int k = threadIdx.x; k < HID; k += 256) {
            const float v = (r < 20) ? WH[((size_t)s * HID + k) * 4 + a] : 0.f;
            const int c = k >> 7, o = (k >> 3) & 15, j = k & 7;
            const int sw = (o & 8) | ((o & 7) ^ (r & 7));
            WHT[(size_t)r * HID + c * 128 + sw * 8 + j] = (__bf16)v;
        }
    }
}

// ---------------------------------------------------------------------------
// Pure m97-form GEMM + fused head (r6-r9 verified: 153 us, ~900 TF eff).
// BYTE-IDENTICAL to round 9's policy_main. 256 threads / 4 waves, 128x128
// tile, BK=64, A (=H) and B (=W2T) via global_load_lds width-16, 2 barriers
// per iter, LDS 40960 B -> 4 blocks/CU. XCD grouping: n8 = blockIdx>>mg_bits.
// ---------------------------------------------------------------------------
__global__ __launch_bounds__(256, 4)
void policy_main(const __bf16* __restrict__ H, const int* __restrict__ SK,
                 const __bf16* __restrict__ W2T, const float* __restrict__ B2,
                 const __bf16* __restrict__ WHT, const float* __restrict__ BH,
                 float* __restrict__ OUT, int row0, int mg_bits) {
    __shared__ __align__(16) char smem[40960];
    __bf16* hA    = (__bf16*)smem;            // [128][64]
    __bf16* Bt    = (__bf16*)(smem + 16384);  // [128][64]
    __bf16* featL = (__bf16*)smem;            // overlay [128][128] swizzled
    __bf16* WHTL  = (__bf16*)(smem + 32768);  // [32][128]

    const int tid  = threadIdx.x;
    const int lane = tid & 63;
    const int wv   = tid >> 6;   // 0..3
    const int wm   = wv & 1;     // sample strip of 64
    const int wn   = wv >> 1;    // featcol strip of 64
    const int l15  = lane & 15;
    const int quad = lane >> 4;
    const int n8   = blockIdx.x >> mg_bits;
    const int i0l  = (blockIdx.x & ((1 << mg_bits) - 1)) * MT;  // chunk-local

    floatx4 acc[4][4] = {};    // [fn featcol-frag][fm sample-frag]
    floatx4 hacc[2][2] = {};   // head acc [sample-frag][headcol-tile]

    // ---- prologue: stage WHTL [32][128] once (kt-invariant)
#pragma unroll
    for (int c = 0; c < 2; ++c) {
        const int rb = c * 16 + wv * 4;
        const __bf16* gp = WHT + (size_t)(rb + (lane >> 4)) * HID
                         + n8 * 128 + (lane & 15) * 8;
        __builtin_amdgcn_global_load_lds((GLOBAL_AS void*)gp,
                                         (LOCAL_AS void*)(WHTL + rb * 128), 16, 0, 0);
    }

#pragma unroll 1
    for (int kt = 0; kt < KIT; ++kt) {
        __syncthreads();  // previous iter's frag readers done
        // ---- stage A from H: 4 global_load_lds per thread
#pragma unroll
        for (int c = 0; c < 4; ++c) {
            const int rb = c * 32 + wv * 8;
            const __bf16* gp = H + (size_t)(i0l + rb + (lane >> 3)) * HID
                             + kt * BK + (lane & 7) * 8;
            __builtin_amdgcn_global_load_lds((GLOBAL_AS void*)gp,
                                             (LOCAL_AS void*)(hA + rb * 64), 16, 0, 0);
        }
        // ---- stage B from W2T slab n8
#pragma unroll
        for (int c = 0; c < 4; ++c) {
            const int rb = c * 32 + wv * 8;
            const __bf16* gp = W2T + (size_t)(n8 * 128 + rb + (lane >> 3)) * HID
                             + kt * BK + (lane & 7) * 8;
            __builtin_amdgcn_global_load_lds((GLOBAL_AS void*)gp,
                                             (LOCAL_AS void*)(Bt + rb * 64), 16, 0, 0);
        }
        __syncthreads();  // drain staging
        // ---- 2 k-steps of 32: 8 frag reads + 16 MFMA each
#pragma unroll
        for (int ks = 0; ks < 2; ++ks) {
            bf16x8 wf[4], hf[4];
#pragma unroll
            for (int f = 0; f < 4; ++f) {
                const int row = wn * 64 + f * 16 + l15;   // featcol (local)
                wf[f] = *(const bf16x8*)(Bt + row * 64 + (((ks * 4 + quad) ^ (row & 7)) * 8));
            }
#pragma unroll
            for (int f = 0; f < 4; ++f) {
                const int smp = wm * 64 + f * 16 + l15;
                hf[f] = *(const bf16x8*)(hA + smp * 64 + (((ks * 4 + quad) ^ (smp & 7)) * 8));
            }
#pragma unroll
            for (int fn = 0; fn < 4; ++fn)
#pragma unroll
                for (int fm = 0; fm < 4; ++fm)
                    acc[fn][fm] = __builtin_amdgcn_mfma_f32_16x16x32_bf16(
                        wf[fn], hf[fm], acc[fn][fm], 0, 0, 0);
        }
    }

    // ---- epilogue: relu(acc+b2) -> featL (swizzled, overlays hA+Bt)
    __syncthreads();  // K-loop frag readers done before overlay
#pragma unroll
    for (int fn = 0; fn < 4; ++fn) {
        const int fcb = wn * 64 + fn * 16 + quad * 4;   // featcol base 0..124
        const float4 b2v = *(const float4*)(B2 + n8 * 128 + fcb);
#pragma unroll
        for (int fm = 0; fm < 4; ++fm) {
            const int smp = wm * 64 + fm * 16 + l15;
            const floatx4 v = acc[fn][fm];
            bf16x4 p;
            p[0] = (__bf16)fmaxf(v[0] + b2v.x, 0.f);
            p[1] = (__bf16)fmaxf(v[1] + b2v.y, 0.f);
            p[2] = (__bf16)fmaxf(v[2] + b2v.z, 0.f);
            p[3] = (__bf16)fmaxf(v[3] + b2v.w, 0.f);
            *(bf16x4*)(featL + smp * 128 + (((fcb >> 3) ^ (smp & 15)) << 3) + (fcb & 7)) = p;
        }
    }
    __syncthreads();

    // ---- head MFMA: wave w -> samples w*32..+31, K = this block's 128 cols
#pragma unroll
    for (int f2 = 0; f2 < 2; ++f2) {
#pragma unroll
        for (int ks2 = 0; ks2 < 4; ++ks2) {
            const int row = wv * 32 + f2 * 16 + l15;
            const bf16x8 fa = *(const bf16x8*)(featL + row * 128
                                 + (((ks2 * 4 + quad) ^ (row & 15)) << 3));
#pragma unroll
            for (int t2 = 0; t2 < 2; ++t2) {
                const int r = t2 * 16 + l15;
                const int o = ks2 * 4 + quad;
                const int sw = (o & 8) | ((o & 7) ^ (r & 7));
                const bf16x8 wb = *(const bf16x8*)(WHTL + r * 128 + sw * 8);
                hacc[f2][t2] = __builtin_amdgcn_mfma_f32_16x16x32_bf16(
                    fa, wb, hacc[f2][t2], 0, 0, 0);
            }
        }
    }

    // ---- atomic scatter from registers: C-layout sample = quad*4+reg,
    //      headcol = t2*16 + l15; emit only the selected skill's 4 actions
#pragma unroll
    for (int f2 = 0; f2 < 2; ++f2)
#pragma unroll
        for (int j = 0; j < 4; ++j) {
            const int smp = wv * 32 + f2 * 16 + quad * 4 + j;
            const int sk  = SK[(size_t)row0 + i0l + smp];
#pragma unroll
            for (int t2 = 0; t2 < 2; ++t2) {
                const int hc = t2 * 16 + l15;
                const int d  = hc - sk * 4;
                if (d >= 0 && d < 4) {
                    float v = hacc[f2][t2][j];
                    if (n8 == 0) v += BH[hc];
                    atomicAdd(&OUT[(size_t)(row0 + i0l + smp) * 4 + d], v);
                }
            }
        }
}

extern "C" void kernel_launch(void* const* d_in, const int* in_sizes, int n_in,
                              void* d_out, int out_size, void* d_ws, size_t ws_size,
                              hipStream_t stream) {
    const float* S  = (const float*)d_in[0];
    const int*   SK = (const int*)d_in[1];
    const float* W1 = (const float*)d_in[2];
    const float* B1 = (const float*)d_in[3];
    const float* W2 = (const float*)d_in[4];
    const float* B2 = (const float*)d_in[5];
    const float* WH = (const float*)d_in[6];
    const float* BH = (const float*)d_in[7];

    char* ws = (char*)d_ws;
    __bf16* W2T = (__bf16*)ws;                          // 2 MiB
    __bf16* WHT = (__bf16*)(ws + 2 * 1024 * 1024);      // 64 KiB
    __bf16* H   = (__bf16*)(ws + 2 * 1024 * 1024 + 65536);

    // chunk the batch so H fits in the workspace (deterministic per call)
    const size_t fixed = 2 * 1024 * 1024 + 65536;
    const size_t avail = ws_size > fixed ? ws_size - fixed : 0;
    int nc = 1;
    while (nc < 64 && (size_t)(65536 / nc) * HID * sizeof(__bf16) > avail) nc <<= 1;
    const int Mc = 65536 / nc;
    int mg_bits = 0;
    while ((1 << mg_bits) < Mc / MT) ++mg_bits;   // Mc/MT is a power of two

    for (int c = 0; c < nc; ++c) {
        const int nh = Mc / 32;                   // H blocks (8 rows/wave)
        const int nz = Mc / 256;                  // OUT-zero blocks
        const int extra = (c == 0) ? 288 : 0;     // weight preps once, last
        hipLaunchKernelGGL(prep_all, dim3(nh + nz + extra), dim3(256), 0, stream,
                           S, W1, B1, W2, WH, H, W2T, WHT, (float*)d_out,
                           c * Mc, nh, nz);
        hipLaunchKernelGGL(policy_main, dim3((Mc / MT) * 8), dim3(256), 0, stream,
                           H, SK, W2T, B2, WHT, BH, (float*)d_out, c * Mc, mg_bits);
    }
}